// Round 4
// baseline (472.248 us; speedup 1.0000x reference)
//
#include <hip/hip_runtime.h>
#include <hip/hip_bf16.h>
#include <stdint.h>

#define TT 8192   // tokens
#define HH 1024   // hidden
#define II 2048   // intermediate
#define EE 8      // experts
#define TOPK 2

typedef __bf16 bf16x8 __attribute__((ext_vector_type(8)));
typedef float f32x4 __attribute__((ext_vector_type(4)));

__device__ __forceinline__ unsigned short f2bf(float f) {
  union { float f; unsigned int u; } c; c.f = f;
  unsigned int u = c.u;
  u += 0x7FFFu + ((u >> 16) & 1u);   // RNE
  return (unsigned short)(u >> 16);
}

__device__ __forceinline__ void gload_lds16(const void* g, void* l) {
  __builtin_amdgcn_global_load_lds((const __attribute__((address_space(1))) void*)g,
                                   (__attribute__((address_space(3))) void*)l, 16, 0, 0);
}

#define SBAR()  do { __builtin_amdgcn_sched_barrier(0); __builtin_amdgcn_s_barrier(); \
                     __builtin_amdgcn_sched_barrier(0); } while (0)
#define LGKM0() do { asm volatile("s_waitcnt lgkmcnt(0)" ::: "memory"); \
                     __builtin_amdgcn_sched_barrier(0); } while (0)

// -------- transpose + convert: src [E][R][C] fp32 -> dst [E][C][R] bf16 --------
__global__ __launch_bounds__(256) void k_transpose_cvt(const float* __restrict__ src,
                                                       unsigned short* __restrict__ dst,
                                                       int R, int C) {
  __shared__ float tile[64][65];
  const float* s = src + (size_t)blockIdx.z * R * C;
  unsigned short* d = dst + (size_t)blockIdx.z * R * C;
  int r0 = blockIdx.y * 64, c0 = blockIdx.x * 64;
  int tx = threadIdx.x & 15;
  int ty = threadIdx.x >> 4;
#pragma unroll
  for (int i = 0; i < 4; ++i) {
    int rr = i * 16 + ty;
    float4 v = *reinterpret_cast<const float4*>(&s[(size_t)(r0 + rr) * C + c0 + tx * 4]);
    tile[rr][tx * 4 + 0] = v.x; tile[rr][tx * 4 + 1] = v.y;
    tile[rr][tx * 4 + 2] = v.z; tile[rr][tx * 4 + 3] = v.w;
  }
  __syncthreads();
#pragma unroll
  for (int i = 0; i < 4; ++i) {
    int cc = i * 16 + ty;
    ushort4 o;
    o.x = f2bf(tile[tx * 4 + 0][cc]);
    o.y = f2bf(tile[tx * 4 + 1][cc]);
    o.z = f2bf(tile[tx * 4 + 2][cc]);
    o.w = f2bf(tile[tx * 4 + 3][cc]);
    *reinterpret_cast<ushort4*>(&d[(size_t)(c0 + cc) * R + r0 + tx * 4]) = o;
  }
}

// ---------------- router: logits, top-2, sigmoid-renorm, expert lists ----------------
__global__ __launch_bounds__(256) void k_router(const float* __restrict__ x,
                                                const float* __restrict__ Wr,
                                                const float* __restrict__ br,
                                                unsigned short* __restrict__ xb,
                                                int* __restrict__ tlist,
                                                float* __restrict__ glist,
                                                int* __restrict__ counts) {
  __shared__ float wrt[8][1024];
  __shared__ int lcount[8];
  __shared__ int lbase[8];
  __shared__ short ent_e[128];
  __shared__ short ent_slot[128];
  __shared__ float ent_g[128];
  int tid = threadIdx.x;
  for (int i = tid; i < 8192; i += 256) {
    wrt[i & 7][i >> 3] = Wr[i];
  }
  if (tid < 8) lcount[tid] = 0;
  __syncthreads();
  int w = tid >> 6, l = tid & 63;
  int t0 = blockIdx.x * 64;
  for (int it = 0; it < 16; ++it) {
    int t = t0 + w * 16 + it;
    const float4* xr = reinterpret_cast<const float4*>(x + (size_t)t * HH);
    float acc[8] = {0.f, 0.f, 0.f, 0.f, 0.f, 0.f, 0.f, 0.f};
#pragma unroll
    for (int j = 0; j < 4; ++j) {
      float4 xv = xr[j * 64 + l];
      int hbase = (j * 64 + l) * 4;
      ushort4 o;
      o.x = f2bf(xv.x); o.y = f2bf(xv.y); o.z = f2bf(xv.z); o.w = f2bf(xv.w);
      *reinterpret_cast<ushort4*>(xb + (size_t)t * HH + hbase) = o;
#pragma unroll
      for (int e = 0; e < 8; ++e) {
        float4 wv = *reinterpret_cast<const float4*>(&wrt[e][hbase]);
        acc[e] += xv.x * wv.x + xv.y * wv.y + xv.z * wv.z + xv.w * wv.w;
      }
    }
#pragma unroll
    for (int e = 0; e < 8; ++e)
#pragma unroll
      for (int off = 32; off > 0; off >>= 1) acc[e] += __shfl_xor(acc[e], off, 64);
    if (l == 0) {
      float lg[8];
#pragma unroll
      for (int e = 0; e < 8; ++e) lg[e] = acc[e] + br[e];
      int i0 = 0;
#pragma unroll
      for (int e = 1; e < 8; ++e) if (lg[e] > lg[i0]) i0 = e;
      int i1 = (i0 == 0) ? 1 : 0;
#pragma unroll
      for (int e = 0; e < 8; ++e) if (e != i0 && lg[e] > lg[i1]) i1 = e;
      float g0 = 1.f / (1.f + expf(-lg[i0]));
      float g1 = 1.f / (1.f + expf(-lg[i1]));
      float inv = 1.f / (g0 + g1 + 1e-10f);
      int idx = (w * 16 + it) * 2;
      int s0 = atomicAdd(&lcount[i0], 1);
      ent_e[idx] = (short)i0; ent_slot[idx] = (short)s0; ent_g[idx] = g0 * inv;
      int s1 = atomicAdd(&lcount[i1], 1);
      ent_e[idx + 1] = (short)i1; ent_slot[idx + 1] = (short)s1; ent_g[idx + 1] = g1 * inv;
    }
  }
  __syncthreads();
  if (tid < 8) lbase[tid] = atomicAdd(&counts[tid], lcount[tid]);
  __syncthreads();
  if (tid < 128) {
    int e = ent_e[tid];
    int slot = lbase[e] + ent_slot[tid];
    int t = t0 + (tid >> 1);
    tlist[e * TT + slot] = t;
    glist[e * TT + slot] = ent_g[tid];
  }
}

__global__ void k_offsets(const int* __restrict__ counts, int* __restrict__ offs) {
  if (threadIdx.x == 0) {
    int s = 0;
    for (int e = 0; e < EE; ++e) { offs[e] = s; s += counts[e]; }
  }
}

// ---------------- GEMM1: h = silu(x@Wg) * (x@Wu) * gate ----------------
// BM=256, BN=128, BK=32, 8 waves (2M x 4N, per-wave 128x32 dual-output).
// Triple-buffered LDS slots (3 x 32 KiB): compute tile t (slot t%3) while
// staging tile t+2 into slot (t+2)%3 (= slot of t-1, freed at end of t-1).
// 2 phases/K-tile: {ds_read frags | 2 stage calls | barrier | lgkmcnt(0) |
// setprio(1) 16 MFMA setprio(0) | barrier}. End-of-tile: vmcnt(4) (tile t+1
// landed, t+2 in flight across the barrier) -- counted, never 0 mid-loop.
// BK=32 row stride (64B) makes frag ds_read_b128 conflict-free (64 chunks
// uniform over 8 bank groups) -- no swizzle needed.
__global__ __launch_bounds__(512, 2) void k_gemm1(
    const unsigned short* __restrict__ xb,
    const unsigned short* __restrict__ WgT,
    const unsigned short* __restrict__ WuT,
    const int* __restrict__ tlist, const float* __restrict__ glist,
    const int* __restrict__ counts, const int* __restrict__ offs,
    unsigned short* __restrict__ hbuf) {
  __shared__ unsigned short lsA[3][256 * 32];   // 48 KB
  __shared__ unsigned short lsG[3][128 * 32];   // 24 KB
  __shared__ unsigned short lsU[3][128 * 32];   // 24 KB
  __shared__ int s_tok[256];
  __shared__ float s_gate[256];

  const int e = blockIdx.z;
  const int n_e = counts[e];
  const int row0 = blockIdx.y * 256;
  if (row0 >= n_e) return;
  const int n0 = blockIdx.x * 128;
  const int tid = threadIdx.x;

  if (tid < 256) {
    int r = row0 + tid;
    int tok = 0; float gt = 0.f;
    if (r < n_e) { tok = tlist[e * TT + r]; gt = glist[e * TT + r]; }
    s_tok[tid] = tok; s_gate[tid] = gt;
  }
  __syncthreads();

  // per-thread stage sources: row = tid>>2 (128 rows/call), 16B chunk = tid&3
  const int srow = tid >> 2;
  const int scol = (tid & 3) * 8;
  const unsigned short* sA0 = xb + (size_t)s_tok[srow] * HH + scol;
  const unsigned short* sA1 = xb + (size_t)s_tok[128 + srow] * HH + scol;
  const unsigned short* sG  = WgT + ((size_t)e * II + n0 + srow) * HH + scol;
  const unsigned short* sU  = WuT + ((size_t)e * II + n0 + srow) * HH + scol;

  f32x4 zero = {0.f, 0.f, 0.f, 0.f};
  f32x4 accg[8][2], accu[8][2];
#pragma unroll
  for (int m = 0; m < 8; ++m)
#pragma unroll
    for (int n = 0; n < 2; ++n) { accg[m][n] = zero; accu[m][n] = zero; }

  const int l = tid & 63;
  const int w = tid >> 6;
  const int wr = (w >> 2) * 128;   // 0 or 128
  const int wc = (w & 3) * 32;     // 0,32,64,96
  const int lrow = l & 15;
  const int lk = l >> 4;
  const int aoff = (wr + lrow) * 64 + lk * 16;
  const int boff = (wc + lrow) * 64 + lk * 16;

  // prologue: tiles 0,1 -> slots 0,1
#pragma unroll
  for (int t = 0; t < 2; ++t) {
    gload_lds16(sA0 + t * 32, (char*)&lsA[t][0] + tid * 16);
    gload_lds16(sA1 + t * 32, (char*)&lsA[t][0] + 8192 + tid * 16);
    gload_lds16(sG + t * 32, (char*)&lsG[t][0] + tid * 16);
    gload_lds16(sU + t * 32, (char*)&lsU[t][0] + tid * 16);
  }
  asm volatile("s_waitcnt vmcnt(4)" ::: "memory");   // tile 0 landed
  SBAR();

  int slot = 0;
#pragma unroll 1
  for (int t = 0; t < HH / 32; ++t) {
    int ss = slot + 2; if (ss >= 3) ss -= 3;         // stage slot = (t+2)%3
    const char* lA = (const char*)&lsA[slot][0];
    const char* lG = (const char*)&lsG[slot][0];
    const char* lU = (const char*)&lsU[slot][0];
    const bool pf = (t < HH / 32 - 2);

    // ---- phase 1: m0..3 ----
    bf16x8 af[4], bg[2], bu[2];
#pragma unroll
    for (int m = 0; m < 4; ++m) af[m] = *(const bf16x8*)(lA + aoff + m * 1024);
#pragma unroll
    for (int n = 0; n < 2; ++n) {
      bg[n] = *(const bf16x8*)(lG + boff + n * 1024);
      bu[n] = *(const bf16x8*)(lU + boff + n * 1024);
    }
    if (pf) {
      gload_lds16(sA0 + (t + 2) * 32, (char*)&lsA[ss][0] + tid * 16);
      gload_lds16(sA1 + (t + 2) * 32, (char*)&lsA[ss][0] + 8192 + tid * 16);
    }
    SBAR();
    LGKM0();
    __builtin_amdgcn_s_setprio(1);
#pragma unroll
    for (int m = 0; m < 4; ++m)
#pragma unroll
      for (int n = 0; n < 2; ++n) {
        accg[m][n] = __builtin_amdgcn_mfma_f32_16x16x32_bf16(af[m], bg[n], accg[m][n], 0, 0, 0);
        accu[m][n] = __builtin_amdgcn_mfma_f32_16x16x32_bf16(af[m], bu[n], accu[m][n], 0, 0, 0);
      }
    __builtin_amdgcn_s_setprio(0);
    SBAR();

    // ---- phase 2: m4..7 (bg/bu reused in regs) ----
    bf16x8 af2[4];
#pragma unroll
    for (int m = 0; m < 4; ++m) af2[m] = *(const bf16x8*)(lA + aoff + (m + 4) * 1024);
    if (pf) {
      gload_lds16(sG + (t + 2) * 32, (char*)&lsG[ss][0] + tid * 16);
      gload_lds16(sU + (t + 2) * 32, (char*)&lsU[ss][0] + tid * 16);
    }
    LGKM0();
    __builtin_amdgcn_s_setprio(1);
#pragma unroll
    for (int m = 0; m < 4; ++m)
#pragma unroll
      for (int n = 0; n < 2; ++n) {
        accg[m + 4][n] = __builtin_amdgcn_mfma_f32_16x16x32_bf16(af2[m], bg[n], accg[m + 4][n], 0, 0, 0);
        accu[m + 4][n] = __builtin_amdgcn_mfma_f32_16x16x32_bf16(af2[m], bu[n], accu[m + 4][n], 0, 0, 0);
      }
    __builtin_amdgcn_s_setprio(0);
    __builtin_amdgcn_sched_barrier(0);
    if (pf) { asm volatile("s_waitcnt vmcnt(4)" ::: "memory"); }   // t+1 landed, t+2 flying
    else    { asm volatile("s_waitcnt vmcnt(0)" ::: "memory"); }
    SBAR();
    slot = (slot == 2) ? 0 : slot + 1;
  }

  const int obase = offs[e];
#pragma unroll
  for (int m = 0; m < 8; ++m)
#pragma unroll
    for (int n = 0; n < 2; ++n)
#pragma unroll
      for (int r = 0; r < 4; ++r) {
        int rl = wr + m * 16 + lk * 4 + r;   // C/D: col=lane&15, row=(lane>>4)*4+reg
        if (row0 + rl < n_e) {
          float gv = accg[m][n][r];
          float uv = accu[m][n][r];
          float val = gv / (1.f + __expf(-gv)) * uv * s_gate[rl];
          hbuf[(size_t)(obase + row0 + rl) * II + n0 + wc + n * 16 + lrow] = f2bf(val);
        }
      }
}

// ---------------- GEMM2: out += h @ Wd (same engine, atomic-scatter epilogue) ----
// BM=256, BN=256, BK=32, per-wave 128x64, K-tiles=64.
__global__ __launch_bounds__(512, 2) void k_gemm2(
    const unsigned short* __restrict__ hbuf,
    const unsigned short* __restrict__ WdT,   // [E][H][I] (k=I contiguous)
    const int* __restrict__ tlist,
    const int* __restrict__ counts, const int* __restrict__ offs,
    float* __restrict__ out) {
  __shared__ unsigned short lsA[3][256 * 32];   // 48 KB
  __shared__ unsigned short lsB[3][256 * 32];   // 48 KB
  __shared__ int s_tok[256];

  const int e = blockIdx.z;
  const int n_e = counts[e];
  const int row0 = blockIdx.y * 256;
  if (row0 >= n_e) return;
  const int n0 = blockIdx.x * 256;
  const int tid = threadIdx.x;
  const int obase = offs[e];

  if (tid < 256) {
    int r = row0 + tid;
    s_tok[tid] = (r < n_e) ? tlist[e * TT + r] : 0;
  }
  __syncthreads();

  const int srow = tid >> 2;
  const int scol = (tid & 3) * 8;
  int ar0 = obase + row0 + srow;       if (ar0 > TT * TOPK - 1) ar0 = TT * TOPK - 1;
  int ar1 = obase + row0 + 128 + srow; if (ar1 > TT * TOPK - 1) ar1 = TT * TOPK - 1;
  const unsigned short* sA0 = hbuf + (size_t)ar0 * II + scol;
  const unsigned short* sA1 = hbuf + (size_t)ar1 * II + scol;
  const unsigned short* sB0 = WdT + ((size_t)e * HH + n0 + srow) * II + scol;
  const unsigned short* sB1 = WdT + ((size_t)e * HH + n0 + 128 + srow) * II + scol;

  f32x4 zero = {0.f, 0.f, 0.f, 0.f};
  f32x4 acc[8][4];
#pragma unroll
  for (int m = 0; m < 8; ++m)
#pragma unroll
    for (int n = 0; n < 4; ++n) acc[m][n] = zero;

  const int l = tid & 63;
  const int w = tid >> 6;
  const int wr = (w >> 2) * 128;   // 0 or 128
  const int wc = (w & 3) * 64;     // 0,64,128,192
  const int lrow = l & 15;
  const int lk = l >> 4;
  const int aoff = (wr + lrow) * 64 + lk * 16;
  const int boff = (wc + lrow) * 64 + lk * 16;

#pragma unroll
  for (int t = 0; t < 2; ++t) {
    gload_lds16(sA0 + t * 32, (char*)&lsA[t][0] + tid * 16);
    gload_lds16(sA1 + t * 32, (char*)&lsA[t][0] + 8192 + tid * 16);
    gload_lds16(sB0 + t * 32, (char*)&lsB[t][0] + tid * 16);
    gload_lds16(sB1 + t * 32, (char*)&lsB[t][0] + 8192 + tid * 16);
  }
  asm volatile("s_waitcnt vmcnt(4)" ::: "memory");
  SBAR();

  int slot = 0;
#pragma unroll 1
  for (int t = 0; t < II / 32; ++t) {
    int ss = slot + 2; if (ss >= 3) ss -= 3;
    const char* lA = (const char*)&lsA[slot][0];
    const char* lB = (const char*)&lsB[slot][0];
    const bool pf = (t < II / 32 - 2);

    // ---- phase 1: m0..3 x n0..3 ----
    bf16x8 af[4], bb[4];
#pragma unroll
    for (int m = 0; m < 4; ++m) af[m] = *(const bf16x8*)(lA + aoff + m * 1024);
#pragma unroll
    for (int n = 0; n < 4; ++n) bb[n] = *(const bf16x8*)(lB + boff + n * 1024);
    if (pf) {
      gload_lds16(sA0 + (t + 2) * 32, (char*)&lsA[ss][0] + tid * 16);
      gload_lds16(sA1 + (t + 2) * 32, (char*)&lsA[ss][0] + 8192 + tid * 16);
    }
    SBAR();
    LGKM0();
    __builtin_amdgcn_s_setprio(1);
#pragma unroll
    for (int m = 0; m < 4; ++m)
#pragma unroll
      for (int n = 0; n < 4; ++n)
        acc[m][n] = __builtin_amdgcn_mfma_f32_16x16x32_bf16(af[m], bb[n], acc[m][n], 0, 0, 0);
    __builtin_amdgcn_s_setprio(0);
    SBAR();

    // ---- phase 2: m4..7 (bb reused) ----
    bf16x8 af2[4];
#pragma unroll
    for (int m = 0; m < 4; ++m) af2[m] = *(const bf16x8*)(lA + aoff + (m + 4) * 1024);
    if (pf) {
      gload_lds16(sB0 + (t + 2) * 32, (char*)&lsB[ss][0] + tid * 16);
      gload_lds16(sB1 + (t + 2) * 32, (char*)&lsB[ss][0] + 8192 + tid * 16);
    }
    LGKM0();
    __builtin_amdgcn_s_setprio(1);
#pragma unroll
    for (int m = 0; m < 4; ++m)
#pragma unroll
      for (int n = 0; n < 4; ++n)
        acc[m + 4][n] = __builtin_amdgcn_mfma_f32_16x16x32_bf16(af2[m], bb[n], acc[m + 4][n], 0, 0, 0);
    __builtin_amdgcn_s_setprio(0);
    __builtin_amdgcn_sched_barrier(0);
    if (pf) { asm volatile("s_waitcnt vmcnt(4)" ::: "memory"); }
    else    { asm volatile("s_waitcnt vmcnt(0)" ::: "memory"); }
    SBAR();
    slot = (slot == 2) ? 0 : slot + 1;
  }

#pragma unroll
  for (int m = 0; m < 8; ++m)
#pragma unroll
    for (int n = 0; n < 4; ++n)
#pragma unroll
      for (int r = 0; r < 4; ++r) {
        int rl = wr + m * 16 + lk * 4 + r;
        if (row0 + rl < n_e) {
          int tkn = s_tok[rl];
          unsafeAtomicAdd(&out[(size_t)tkn * HH + n0 + wc + n * 16 + lrow], acc[m][n][r]);
        }
      }
}

extern "C" void kernel_launch(void* const* d_in, const int* in_sizes, int n_in,
                              void* d_out, int out_size, void* d_ws, size_t ws_size,
                              hipStream_t stream) {
  const float* x  = (const float*)d_in[0];
  const float* Wr = (const float*)d_in[1];
  const float* br = (const float*)d_in[2];
  const float* Wg = (const float*)d_in[3];
  const float* Wu = (const float*)d_in[4];
  const float* Wd = (const float*)d_in[5];
  float* out = (float*)d_out;

  char* ws = (char*)d_ws;
  size_t off = 0;
  auto alloc = [&](size_t bytes) {
    char* p = ws + off;
    off += (bytes + 255) & ~(size_t)255;
    return p;
  };
  unsigned short* xb   = (unsigned short*)alloc((size_t)TT * HH * 2);        // 16 MB
  unsigned short* WgT  = (unsigned short*)alloc((size_t)EE * HH * II * 2);   // 32 MB
  unsigned short* WuT  = (unsigned short*)alloc((size_t)EE * HH * II * 2);   // 32 MB
  unsigned short* WdT  = (unsigned short*)alloc((size_t)EE * HH * II * 2);   // 32 MB
  unsigned short* hbuf = (unsigned short*)alloc((size_t)TT * TOPK * II * 2); // 64 MB
  int*   tlist  = (int*)alloc((size_t)EE * TT * 4);
  float* glist  = (float*)alloc((size_t)EE * TT * 4);
  int*   counts = (int*)alloc(128);
  int*   offs   = (int*)alloc(128);

  hipMemsetAsync(counts, 0, 128, stream);
  hipMemsetAsync(d_out, 0, (size_t)TT * HH * 4, stream);

  dim3 tg1(II / 64, HH / 64, EE);   // Wg/Wu: [H][I] -> [I][H]
  k_transpose_cvt<<<tg1, 256, 0, stream>>>(Wg, WgT, HH, II);
  k_transpose_cvt<<<tg1, 256, 0, stream>>>(Wu, WuT, HH, II);
  dim3 tg2(HH / 64, II / 64, EE);   // Wd: [I][H] -> [H][I]
  k_transpose_cvt<<<tg2, 256, 0, stream>>>(Wd, WdT, II, HH);

  k_router<<<TT / 64, 256, 0, stream>>>(x, Wr, br, xb, tlist, glist, counts);
  k_offsets<<<1, 64, 0, stream>>>(counts, offs);

  dim3 g1(II / 128, 32, EE);        // 256-row tiles, worst case 8192 rows/expert
  k_gemm1<<<g1, 512, 0, stream>>>(xb, WgT, WuT, tlist, glist, counts, offs, hbuf);
  dim3 g2(HH / 256, 32, EE);
  k_gemm2<<<g2, 512, 0, stream>>>(hbuf, WdT, tlist, counts, offs, out);

  (void)in_sizes; (void)n_in; (void)out_size; (void)ws_size;
}

// Round 5
// 460.335 us; speedup vs baseline: 1.0259x; 1.0259x over previous
//
#include <hip/hip_runtime.h>
#include <hip/hip_bf16.h>
#include <stdint.h>

#define TT 8192   // tokens
#define HH 1024   // hidden
#define II 2048   // intermediate
#define EE 8      // experts
#define TOPK 2

typedef __bf16 bf16x8 __attribute__((ext_vector_type(8)));
typedef float f32x4 __attribute__((ext_vector_type(4)));

__device__ __forceinline__ unsigned short f2bf(float f) {
  union { float f; unsigned int u; } c; c.f = f;
  unsigned int u = c.u;
  u += 0x7FFFu + ((u >> 16) & 1u);   // RNE
  return (unsigned short)(u >> 16);
}

__device__ __forceinline__ void gload_lds16(const void* g, void* l) {
  __builtin_amdgcn_global_load_lds((const __attribute__((address_space(1))) void*)g,
                                   (__attribute__((address_space(3))) void*)l, 16, 0, 0);
}

#define SBAR()  do { __builtin_amdgcn_sched_barrier(0); __builtin_amdgcn_s_barrier(); \
                     __builtin_amdgcn_sched_barrier(0); } while (0)
#define LGKM0() do { asm volatile("s_waitcnt lgkmcnt(0)" ::: "memory"); \
                     __builtin_amdgcn_sched_barrier(0); } while (0)

// -------- transpose + convert: src [E][R][C] fp32 -> dst [E][C][R] bf16 --------
__global__ __launch_bounds__(256) void k_transpose_cvt(const float* __restrict__ src,
                                                       unsigned short* __restrict__ dst,
                                                       int R, int C) {
  __shared__ float tile[64][65];
  const float* s = src + (size_t)blockIdx.z * R * C;
  unsigned short* d = dst + (size_t)blockIdx.z * R * C;
  int r0 = blockIdx.y * 64, c0 = blockIdx.x * 64;
  int tx = threadIdx.x & 15;
  int ty = threadIdx.x >> 4;
#pragma unroll
  for (int i = 0; i < 4; ++i) {
    int rr = i * 16 + ty;
    float4 v = *reinterpret_cast<const float4*>(&s[(size_t)(r0 + rr) * C + c0 + tx * 4]);
    tile[rr][tx * 4 + 0] = v.x; tile[rr][tx * 4 + 1] = v.y;
    tile[rr][tx * 4 + 2] = v.z; tile[rr][tx * 4 + 3] = v.w;
  }
  __syncthreads();
#pragma unroll
  for (int i = 0; i < 4; ++i) {
    int cc = i * 16 + ty;
    ushort4 o;
    o.x = f2bf(tile[tx * 4 + 0][cc]);
    o.y = f2bf(tile[tx * 4 + 1][cc]);
    o.z = f2bf(tile[tx * 4 + 2][cc]);
    o.w = f2bf(tile[tx * 4 + 3][cc]);
    *reinterpret_cast<ushort4*>(&d[(size_t)(c0 + cc) * R + r0 + tx * 4]) = o;
  }
}

// ---------------- router: logits, top-2, sigmoid-renorm, expert lists ----------------
__global__ __launch_bounds__(256) void k_router(const float* __restrict__ x,
                                                const float* __restrict__ Wr,
                                                const float* __restrict__ br,
                                                unsigned short* __restrict__ xb,
                                                int* __restrict__ tlist,
                                                float* __restrict__ glist,
                                                int* __restrict__ counts) {
  __shared__ float wrt[8][1024];
  __shared__ int lcount[8];
  __shared__ int lbase[8];
  __shared__ short ent_e[128];
  __shared__ short ent_slot[128];
  __shared__ float ent_g[128];
  int tid = threadIdx.x;
  for (int i = tid; i < 8192; i += 256) {
    wrt[i & 7][i >> 3] = Wr[i];
  }
  if (tid < 8) lcount[tid] = 0;
  __syncthreads();
  int w = tid >> 6, l = tid & 63;
  int t0 = blockIdx.x * 64;
  for (int it = 0; it < 16; ++it) {
    int t = t0 + w * 16 + it;
    const float4* xr = reinterpret_cast<const float4*>(x + (size_t)t * HH);
    float acc[8] = {0.f, 0.f, 0.f, 0.f, 0.f, 0.f, 0.f, 0.f};
#pragma unroll
    for (int j = 0; j < 4; ++j) {
      float4 xv = xr[j * 64 + l];
      int hbase = (j * 64 + l) * 4;
      ushort4 o;
      o.x = f2bf(xv.x); o.y = f2bf(xv.y); o.z = f2bf(xv.z); o.w = f2bf(xv.w);
      *reinterpret_cast<ushort4*>(xb + (size_t)t * HH + hbase) = o;
#pragma unroll
      for (int e = 0; e < 8; ++e) {
        float4 wv = *reinterpret_cast<const float4*>(&wrt[e][hbase]);
        acc[e] += xv.x * wv.x + xv.y * wv.y + xv.z * wv.z + xv.w * wv.w;
      }
    }
#pragma unroll
    for (int e = 0; e < 8; ++e)
#pragma unroll
      for (int off = 32; off > 0; off >>= 1) acc[e] += __shfl_xor(acc[e], off, 64);
    if (l == 0) {
      float lg[8];
#pragma unroll
      for (int e = 0; e < 8; ++e) lg[e] = acc[e] + br[e];
      int i0 = 0;
#pragma unroll
      for (int e = 1; e < 8; ++e) if (lg[e] > lg[i0]) i0 = e;
      int i1 = (i0 == 0) ? 1 : 0;
#pragma unroll
      for (int e = 0; e < 8; ++e) if (e != i0 && lg[e] > lg[i1]) i1 = e;
      float g0 = 1.f / (1.f + expf(-lg[i0]));
      float g1 = 1.f / (1.f + expf(-lg[i1]));
      float inv = 1.f / (g0 + g1 + 1e-10f);
      int idx = (w * 16 + it) * 2;
      int s0 = atomicAdd(&lcount[i0], 1);
      ent_e[idx] = (short)i0; ent_slot[idx] = (short)s0; ent_g[idx] = g0 * inv;
      int s1 = atomicAdd(&lcount[i1], 1);
      ent_e[idx + 1] = (short)i1; ent_slot[idx + 1] = (short)s1; ent_g[idx + 1] = g1 * inv;
    }
  }
  __syncthreads();
  if (tid < 8) lbase[tid] = atomicAdd(&counts[tid], lcount[tid]);
  __syncthreads();
  if (tid < 128) {
    int e = ent_e[tid];
    int slot = lbase[e] + ent_slot[tid];
    int t = t0 + (tid >> 1);
    tlist[e * TT + slot] = t;
    glist[e * TT + slot] = ent_g[tid];
  }
}

__global__ void k_offsets(const int* __restrict__ counts, int* __restrict__ offs) {
  if (threadIdx.x == 0) {
    int s = 0;
    for (int e = 0; e < EE; ++e) { offs[e] = s; s += counts[e]; }
  }
}

// ---------------- GEMM1: h = silu(x@Wg) * (x@Wu) * gate ----------------
// BM=256, BN=128, BK=32, 8 waves, triple-buffered slots, counted vmcnt(4).
// LDS chunk swizzle (T2/G21 both-sides): logical chunk (row,col) stored at
// physical col' = col ^ ((row>>1)&3). Linear LDS dest (global_load_lds
// constraint); staging thread pre-swizzles its GLOBAL source chunk; reads
// apply the same XOR. Per 16-lane group: rows 0-7 hit 8 distinct bank
// quads, rows 8-15 repeat -> 2-way = free (fixes R4's 1.34e7 conflicts).
__global__ __launch_bounds__(512, 2) void k_gemm1(
    const unsigned short* __restrict__ xb,
    const unsigned short* __restrict__ WgT,
    const unsigned short* __restrict__ WuT,
    const int* __restrict__ tlist, const float* __restrict__ glist,
    const int* __restrict__ counts, const int* __restrict__ offs,
    unsigned short* __restrict__ hbuf) {
  __shared__ unsigned short lsA[3][256 * 32];   // 48 KB
  __shared__ unsigned short lsG[3][128 * 32];   // 24 KB
  __shared__ unsigned short lsU[3][128 * 32];   // 24 KB
  __shared__ int s_tok[256];
  __shared__ float s_gate[256];

  const int e = blockIdx.z;
  const int n_e = counts[e];
  const int row0 = blockIdx.y * 256;
  if (row0 >= n_e) return;
  const int n0 = blockIdx.x * 128;
  const int tid = threadIdx.x;

  if (tid < 256) {
    int r = row0 + tid;
    int tok = 0; float gt = 0.f;
    if (r < n_e) { tok = tlist[e * TT + r]; gt = glist[e * TT + r]; }
    s_tok[tid] = tok; s_gate[tid] = gt;
  }
  __syncthreads();

  // staging: row = tid>>2, SOURCE chunk pre-swizzled: (tid&3) ^ ((tid>>3)&3)
  const int srow = tid >> 2;
  const int scol = (((tid & 3) ^ ((tid >> 3) & 3))) * 8;
  const unsigned short* sA0 = xb + (size_t)s_tok[srow] * HH + scol;
  const unsigned short* sA1 = xb + (size_t)s_tok[128 + srow] * HH + scol;
  const unsigned short* sG  = WgT + ((size_t)e * II + n0 + srow) * HH + scol;
  const unsigned short* sU  = WuT + ((size_t)e * II + n0 + srow) * HH + scol;

  f32x4 zero = {0.f, 0.f, 0.f, 0.f};
  f32x4 accg[8][2], accu[8][2];
#pragma unroll
  for (int m = 0; m < 8; ++m)
#pragma unroll
    for (int n = 0; n < 2; ++n) { accg[m][n] = zero; accu[m][n] = zero; }

  const int l = tid & 63;
  const int w = tid >> 6;
  const int wr = (w >> 2) * 128;   // 0 or 128
  const int wc = (w & 3) * 32;     // 0,32,64,96
  const int lrow = l & 15;
  const int lk = l >> 4;
  const int ksw = (lrow >> 1) & 3;              // read-side chunk XOR
  const int aoff = (wr + lrow) * 64 + ((lk ^ ksw) * 16);
  const int boff = (wc + lrow) * 64 + ((lk ^ ksw) * 16);

  // prologue: tiles 0,1 -> slots 0,1
#pragma unroll
  for (int t = 0; t < 2; ++t) {
    gload_lds16(sA0 + t * 32, (char*)&lsA[t][0] + tid * 16);
    gload_lds16(sA1 + t * 32, (char*)&lsA[t][0] + 8192 + tid * 16);
    gload_lds16(sG + t * 32, (char*)&lsG[t][0] + tid * 16);
    gload_lds16(sU + t * 32, (char*)&lsU[t][0] + tid * 16);
  }
  asm volatile("s_waitcnt vmcnt(4)" ::: "memory");   // tile 0 landed
  SBAR();

  int slot = 0;
#pragma unroll 1
  for (int t = 0; t < HH / 32; ++t) {
    int ss = slot + 2; if (ss >= 3) ss -= 3;         // stage slot = (t+2)%3
    const char* lA = (const char*)&lsA[slot][0];
    const char* lG = (const char*)&lsG[slot][0];
    const char* lU = (const char*)&lsU[slot][0];
    const bool pf = (t < HH / 32 - 2);

    // ---- phase 1: m0..3 ----
    bf16x8 af[4], bg[2], bu[2];
#pragma unroll
    for (int m = 0; m < 4; ++m) af[m] = *(const bf16x8*)(lA + aoff + m * 1024);
#pragma unroll
    for (int n = 0; n < 2; ++n) {
      bg[n] = *(const bf16x8*)(lG + boff + n * 1024);
      bu[n] = *(const bf16x8*)(lU + boff + n * 1024);
    }
    if (pf) {
      gload_lds16(sA0 + (t + 2) * 32, (char*)&lsA[ss][0] + tid * 16);
      gload_lds16(sA1 + (t + 2) * 32, (char*)&lsA[ss][0] + 8192 + tid * 16);
    }
    SBAR();
    LGKM0();
    __builtin_amdgcn_s_setprio(1);
#pragma unroll
    for (int m = 0; m < 4; ++m)
#pragma unroll
      for (int n = 0; n < 2; ++n) {
        accg[m][n] = __builtin_amdgcn_mfma_f32_16x16x32_bf16(af[m], bg[n], accg[m][n], 0, 0, 0);
        accu[m][n] = __builtin_amdgcn_mfma_f32_16x16x32_bf16(af[m], bu[n], accu[m][n], 0, 0, 0);
      }
    __builtin_amdgcn_s_setprio(0);
    SBAR();

    // ---- phase 2: m4..7 (bg/bu reused in regs) ----
    bf16x8 af2[4];
#pragma unroll
    for (int m = 0; m < 4; ++m) af2[m] = *(const bf16x8*)(lA + aoff + (m + 4) * 1024);
    if (pf) {
      gload_lds16(sG + (t + 2) * 32, (char*)&lsG[ss][0] + tid * 16);
      gload_lds16(sU + (t + 2) * 32, (char*)&lsU[ss][0] + tid * 16);
    }
    LGKM0();
    __builtin_amdgcn_s_setprio(1);
#pragma unroll
    for (int m = 0; m < 4; ++m)
#pragma unroll
      for (int n = 0; n < 2; ++n) {
        accg[m + 4][n] = __builtin_amdgcn_mfma_f32_16x16x32_bf16(af2[m], bg[n], accg[m + 4][n], 0, 0, 0);
        accu[m + 4][n] = __builtin_amdgcn_mfma_f32_16x16x32_bf16(af2[m], bu[n], accu[m + 4][n], 0, 0, 0);
      }
    __builtin_amdgcn_s_setprio(0);
    __builtin_amdgcn_sched_barrier(0);
    if (pf) { asm volatile("s_waitcnt vmcnt(4)" ::: "memory"); }   // t+1 landed, t+2 flying
    else    { asm volatile("s_waitcnt vmcnt(0)" ::: "memory"); }
    SBAR();
    slot = (slot == 2) ? 0 : slot + 1;
  }

  const int obase = offs[e];
#pragma unroll
  for (int m = 0; m < 8; ++m)
#pragma unroll
    for (int n = 0; n < 2; ++n)
#pragma unroll
      for (int r = 0; r < 4; ++r) {
        int rl = wr + m * 16 + lk * 4 + r;   // C/D: col=lane&15, row=(lane>>4)*4+reg
        if (row0 + rl < n_e) {
          float gv = accg[m][n][r];
          float uv = accu[m][n][r];
          float val = gv / (1.f + __expf(-gv)) * uv * s_gate[rl];
          hbuf[(size_t)(obase + row0 + rl) * II + n0 + wc + n * 16 + lrow] = f2bf(val);
        }
      }
}

// ---------------- GEMM2: out += h @ Wd (same engine, atomic-scatter epilogue) ----
// BM=256, BN=256, BK=32, per-wave 128x64, K-tiles=64. Same chunk swizzle.
__global__ __launch_bounds__(512, 2) void k_gemm2(
    const unsigned short* __restrict__ hbuf,
    const unsigned short* __restrict__ WdT,   // [E][H][I] (k=I contiguous)
    const int* __restrict__ tlist,
    const int* __restrict__ counts, const int* __restrict__ offs,
    float* __restrict__ out) {
  __shared__ unsigned short lsA[3][256 * 32];   // 48 KB
  __shared__ unsigned short lsB[3][256 * 32];   // 48 KB
  __shared__ int s_tok[256];

  const int e = blockIdx.z;
  const int n_e = counts[e];
  const int row0 = blockIdx.y * 256;
  if (row0 >= n_e) return;
  const int n0 = blockIdx.x * 256;
  const int tid = threadIdx.x;
  const int obase = offs[e];

  if (tid < 256) {
    int r = row0 + tid;
    s_tok[tid] = (r < n_e) ? tlist[e * TT + r] : 0;
  }
  __syncthreads();

  const int srow = tid >> 2;
  const int scol = (((tid & 3) ^ ((tid >> 3) & 3))) * 8;
  int ar0 = obase + row0 + srow;       if (ar0 > TT * TOPK - 1) ar0 = TT * TOPK - 1;
  int ar1 = obase + row0 + 128 + srow; if (ar1 > TT * TOPK - 1) ar1 = TT * TOPK - 1;
  const unsigned short* sA0 = hbuf + (size_t)ar0 * II + scol;
  const unsigned short* sA1 = hbuf + (size_t)ar1 * II + scol;
  const unsigned short* sB0 = WdT + ((size_t)e * HH + n0 + srow) * II + scol;
  const unsigned short* sB1 = WdT + ((size_t)e * HH + n0 + 128 + srow) * II + scol;

  f32x4 zero = {0.f, 0.f, 0.f, 0.f};
  f32x4 acc[8][4];
#pragma unroll
  for (int m = 0; m < 8; ++m)
#pragma unroll
    for (int n = 0; n < 4; ++n) acc[m][n] = zero;

  const int l = tid & 63;
  const int w = tid >> 6;
  const int wr = (w >> 2) * 128;   // 0 or 128
  const int wc = (w & 3) * 64;     // 0,64,128,192
  const int lrow = l & 15;
  const int lk = l >> 4;
  const int ksw = (lrow >> 1) & 3;
  const int aoff = (wr + lrow) * 64 + ((lk ^ ksw) * 16);
  const int boff = (wc + lrow) * 64 + ((lk ^ ksw) * 16);

#pragma unroll
  for (int t = 0; t < 2; ++t) {
    gload_lds16(sA0 + t * 32, (char*)&lsA[t][0] + tid * 16);
    gload_lds16(sA1 + t * 32, (char*)&lsA[t][0] + 8192 + tid * 16);
    gload_lds16(sB0 + t * 32, (char*)&lsB[t][0] + tid * 16);
    gload_lds16(sB1 + t * 32, (char*)&lsB[t][0] + 8192 + tid * 16);
  }
  asm volatile("s_waitcnt vmcnt(4)" ::: "memory");
  SBAR();

  int slot = 0;
#pragma unroll 1
  for (int t = 0; t < II / 32; ++t) {
    int ss = slot + 2; if (ss >= 3) ss -= 3;
    const char* lA = (const char*)&lsA[slot][0];
    const char* lB = (const char*)&lsB[slot][0];
    const bool pf = (t < II / 32 - 2);

    // ---- phase 1: m0..3 x n0..3 ----
    bf16x8 af[4], bb[4];
#pragma unroll
    for (int m = 0; m < 4; ++m) af[m] = *(const bf16x8*)(lA + aoff + m * 1024);
#pragma unroll
    for (int n = 0; n < 4; ++n) bb[n] = *(const bf16x8*)(lB + boff + n * 1024);
    if (pf) {
      gload_lds16(sA0 + (t + 2) * 32, (char*)&lsA[ss][0] + tid * 16);
      gload_lds16(sA1 + (t + 2) * 32, (char*)&lsA[ss][0] + 8192 + tid * 16);
    }
    SBAR();
    LGKM0();
    __builtin_amdgcn_s_setprio(1);
#pragma unroll
    for (int m = 0; m < 4; ++m)
#pragma unroll
      for (int n = 0; n < 4; ++n)
        acc[m][n] = __builtin_amdgcn_mfma_f32_16x16x32_bf16(af[m], bb[n], acc[m][n], 0, 0, 0);
    __builtin_amdgcn_s_setprio(0);
    SBAR();

    // ---- phase 2: m4..7 (bb reused) ----
    bf16x8 af2[4];
#pragma unroll
    for (int m = 0; m < 4; ++m) af2[m] = *(const bf16x8*)(lA + aoff + (m + 4) * 1024);
    if (pf) {
      gload_lds16(sB0 + (t + 2) * 32, (char*)&lsB[ss][0] + tid * 16);
      gload_lds16(sB1 + (t + 2) * 32, (char*)&lsB[ss][0] + 8192 + tid * 16);
    }
    LGKM0();
    __builtin_amdgcn_s_setprio(1);
#pragma unroll
    for (int m = 0; m < 4; ++m)
#pragma unroll
      for (int n = 0; n < 4; ++n)
        acc[m + 4][n] = __builtin_amdgcn_mfma_f32_16x16x32_bf16(af2[m], bb[n], acc[m + 4][n], 0, 0, 0);
    __builtin_amdgcn_s_setprio(0);
    __builtin_amdgcn_sched_barrier(0);
    if (pf) { asm volatile("s_waitcnt vmcnt(4)" ::: "memory"); }
    else    { asm volatile("s_waitcnt vmcnt(0)" ::: "memory"); }
    SBAR();
    slot = (slot == 2) ? 0 : slot + 1;
  }

#pragma unroll
  for (int m = 0; m < 8; ++m)
#pragma unroll
    for (int n = 0; n < 4; ++n)
#pragma unroll
      for (int r = 0; r < 4; ++r) {
        int rl = wr + m * 16 + lk * 4 + r;
        if (row0 + rl < n_e) {
          int tkn = s_tok[rl];
          unsafeAtomicAdd(&out[(size_t)tkn * HH + n0 + wc + n * 16 + lrow], acc[m][n][r]);
        }
      }
}

extern "C" void kernel_launch(void* const* d_in, const int* in_sizes, int n_in,
                              void* d_out, int out_size, void* d_ws, size_t ws_size,
                              hipStream_t stream) {
  const float* x  = (const float*)d_in[0];
  const float* Wr = (const float*)d_in[1];
  const float* br = (const float*)d_in[2];
  const float* Wg = (const float*)d_in[3];
  const float* Wu = (const float*)d_in[4];
  const float* Wd = (const float*)d_in[5];
  float* out = (float*)d_out;

  char* ws = (char*)d_ws;
  size_t off = 0;
  auto alloc = [&](size_t bytes) {
    char* p = ws + off;
    off += (bytes + 255) & ~(size_t)255;
    return p;
  };
  unsigned short* xb   = (unsigned short*)alloc((size_t)TT * HH * 2);        // 16 MB
  unsigned short* WgT  = (unsigned short*)alloc((size_t)EE * HH * II * 2);   // 32 MB
  unsigned short* WuT  = (unsigned short*)alloc((size_t)EE * HH * II * 2);   // 32 MB
  unsigned short* WdT  = (unsigned short*)alloc((size_t)EE * HH * II * 2);   // 32 MB
  unsigned short* hbuf = (unsigned short*)alloc((size_t)TT * TOPK * II * 2); // 64 MB
  int*   tlist  = (int*)alloc((size_t)EE * TT * 4);
  float* glist  = (float*)alloc((size_t)EE * TT * 4);
  int*   counts = (int*)alloc(128);
  int*   offs   = (int*)alloc(128);

  hipMemsetAsync(counts, 0, 128, stream);
  hipMemsetAsync(d_out, 0, (size_t)TT * HH * 4, stream);

  dim3 tg1(II / 64, HH / 64, EE);   // Wg/Wu: [H][I] -> [I][H]
  k_transpose_cvt<<<tg1, 256, 0, stream>>>(Wg, WgT, HH, II);
  k_transpose_cvt<<<tg1, 256, 0, stream>>>(Wu, WuT, HH, II);
  dim3 tg2(HH / 64, II / 64, EE);   // Wd: [I][H] -> [H][I]
  k_transpose_cvt<<<tg2, 256, 0, stream>>>(Wd, WdT, II, HH);

  k_router<<<TT / 64, 256, 0, stream>>>(x, Wr, br, xb, tlist, glist, counts);
  k_offsets<<<1, 64, 0, stream>>>(counts, offs);

  dim3 g1(II / 128, 32, EE);        // 256-row tiles, worst case 8192 rows/expert
  k_gemm1<<<g1, 512, 0, stream>>>(xb, WgT, WuT, tlist, glist, counts, offs, hbuf);
  dim3 g2(HH / 256, 32, EE);
  k_gemm2<<<g2, 512, 0, stream>>>(hbuf, WdT, tlist, counts, offs, out);

  (void)in_sizes; (void)n_in; (void)out_size; (void)ws_size;
}

// Round 6
// 390.743 us; speedup vs baseline: 1.2086x; 1.1781x over previous
//
#include <hip/hip_runtime.h>
#include <hip/hip_bf16.h>
#include <stdint.h>

#define TT 8192   // tokens
#define HH 1024   // hidden
#define II 2048   // intermediate
#define EE 8      // experts
#define TOPK 2

typedef __bf16 bf16x8 __attribute__((ext_vector_type(8)));
typedef float f32x4 __attribute__((ext_vector_type(4)));

__device__ __forceinline__ unsigned short f2bf(float f) {
  union { float f; unsigned int u; } c; c.f = f;
  unsigned int u = c.u;
  u += 0x7FFFu + ((u >> 16) & 1u);   // RNE
  return (unsigned short)(u >> 16);
}

__device__ __forceinline__ void gload_lds16(const void* g, void* l) {
  __builtin_amdgcn_global_load_lds((const __attribute__((address_space(1))) void*)g,
                                   (__attribute__((address_space(3))) void*)l, 16, 0, 0);
}

// -------- transpose + convert: src [E][R][C] fp32 -> dst [E][C][R] bf16 --------
__global__ __launch_bounds__(256) void k_transpose_cvt(const float* __restrict__ src,
                                                       unsigned short* __restrict__ dst,
                                                       int R, int C) {
  __shared__ float tile[64][65];
  const float* s = src + (size_t)blockIdx.z * R * C;
  unsigned short* d = dst + (size_t)blockIdx.z * R * C;
  int r0 = blockIdx.y * 64, c0 = blockIdx.x * 64;
  int tx = threadIdx.x & 15;
  int ty = threadIdx.x >> 4;
#pragma unroll
  for (int i = 0; i < 4; ++i) {
    int rr = i * 16 + ty;
    float4 v = *reinterpret_cast<const float4*>(&s[(size_t)(r0 + rr) * C + c0 + tx * 4]);
    tile[rr][tx * 4 + 0] = v.x; tile[rr][tx * 4 + 1] = v.y;
    tile[rr][tx * 4 + 2] = v.z; tile[rr][tx * 4 + 3] = v.w;
  }
  __syncthreads();
#pragma unroll
  for (int i = 0; i < 4; ++i) {
    int cc = i * 16 + ty;
    ushort4 o;
    o.x = f2bf(tile[tx * 4 + 0][cc]);
    o.y = f2bf(tile[tx * 4 + 1][cc]);
    o.z = f2bf(tile[tx * 4 + 2][cc]);
    o.w = f2bf(tile[tx * 4 + 3][cc]);
    *reinterpret_cast<ushort4*>(&d[(size_t)(c0 + cc) * R + r0 + tx * 4]) = o;
  }
}

// ---- transpose Wg/Wu [E][H][I] fp32 -> interleaved WguT [E][2I][H] bf16 ----
// stored row s: gate col j=(s>>5)*16+(s&15) if (s>>4)&1==0, else up col j.
__global__ __launch_bounds__(256) void k_transpose_wgu(const float* __restrict__ src,
                                                       unsigned short* __restrict__ dst,
                                                       int mat) {
  __shared__ float tile[64][65];
  const float* s = src + (size_t)blockIdx.z * HH * II;
  unsigned short* d = dst + (size_t)blockIdx.z * 2 * II * HH;
  int r0 = blockIdx.y * 64, c0 = blockIdx.x * 64;   // r0 over H, c0 over I
  int tx = threadIdx.x & 15;
  int ty = threadIdx.x >> 4;
#pragma unroll
  for (int i = 0; i < 4; ++i) {
    int rr = i * 16 + ty;
    float4 v = *reinterpret_cast<const float4*>(&s[(size_t)(r0 + rr) * II + c0 + tx * 4]);
    tile[rr][tx * 4 + 0] = v.x; tile[rr][tx * 4 + 1] = v.y;
    tile[rr][tx * 4 + 2] = v.z; tile[rr][tx * 4 + 3] = v.w;
  }
  __syncthreads();
#pragma unroll
  for (int i = 0; i < 4; ++i) {
    int cc = i * 16 + ty;
    int srow = c0 * 2 + ((cc >> 4) << 5) + mat * 16 + (cc & 15);
    ushort4 o;
    o.x = f2bf(tile[tx * 4 + 0][cc]);
    o.y = f2bf(tile[tx * 4 + 1][cc]);
    o.z = f2bf(tile[tx * 4 + 2][cc]);
    o.w = f2bf(tile[tx * 4 + 3][cc]);
    *reinterpret_cast<ushort4*>(&d[(size_t)srow * HH + r0 + tx * 4]) = o;
  }
}

// ---------------- router: logits, top-2, sigmoid-renorm, expert lists ----------------
__global__ __launch_bounds__(256) void k_router(const float* __restrict__ x,
                                                const float* __restrict__ Wr,
                                                const float* __restrict__ br,
                                                unsigned short* __restrict__ xb,
                                                int* __restrict__ tlist,
                                                float* __restrict__ glist,
                                                int* __restrict__ counts) {
  __shared__ float wrt[8][1024];
  __shared__ int lcount[8];
  __shared__ int lbase[8];
  __shared__ short ent_e[128];
  __shared__ short ent_slot[128];
  __shared__ float ent_g[128];
  int tid = threadIdx.x;
  for (int i = tid; i < 8192; i += 256) {
    wrt[i & 7][i >> 3] = Wr[i];
  }
  if (tid < 8) lcount[tid] = 0;
  __syncthreads();
  int w = tid >> 6, l = tid & 63;
  int t0 = blockIdx.x * 64;
  for (int it = 0; it < 16; ++it) {
    int t = t0 + w * 16 + it;
    const float4* xr = reinterpret_cast<const float4*>(x + (size_t)t * HH);
    float acc[8] = {0.f, 0.f, 0.f, 0.f, 0.f, 0.f, 0.f, 0.f};
#pragma unroll
    for (int j = 0; j < 4; ++j) {
      float4 xv = xr[j * 64 + l];
      int hbase = (j * 64 + l) * 4;
      ushort4 o;
      o.x = f2bf(xv.x); o.y = f2bf(xv.y); o.z = f2bf(xv.z); o.w = f2bf(xv.w);
      *reinterpret_cast<ushort4*>(xb + (size_t)t * HH + hbase) = o;
#pragma unroll
      for (int e = 0; e < 8; ++e) {
        float4 wv = *reinterpret_cast<const float4*>(&wrt[e][hbase]);
        acc[e] += xv.x * wv.x + xv.y * wv.y + xv.z * wv.z + xv.w * wv.w;
      }
    }
#pragma unroll
    for (int e = 0; e < 8; ++e)
#pragma unroll
      for (int off = 32; off > 0; off >>= 1) acc[e] += __shfl_xor(acc[e], off, 64);
    if (l == 0) {
      float lg[8];
#pragma unroll
      for (int e = 0; e < 8; ++e) lg[e] = acc[e] + br[e];
      int i0 = 0;
#pragma unroll
      for (int e = 1; e < 8; ++e) if (lg[e] > lg[i0]) i0 = e;
      int i1 = (i0 == 0) ? 1 : 0;
#pragma unroll
      for (int e = 0; e < 8; ++e) if (e != i0 && lg[e] > lg[i1]) i1 = e;
      float g0 = 1.f / (1.f + expf(-lg[i0]));
      float g1 = 1.f / (1.f + expf(-lg[i1]));
      float inv = 1.f / (g0 + g1 + 1e-10f);
      int idx = (w * 16 + it) * 2;
      int s0 = atomicAdd(&lcount[i0], 1);
      ent_e[idx] = (short)i0; ent_slot[idx] = (short)s0; ent_g[idx] = g0 * inv;
      int s1 = atomicAdd(&lcount[i1], 1);
      ent_e[idx + 1] = (short)i1; ent_slot[idx + 1] = (short)s1; ent_g[idx + 1] = g1 * inv;
    }
  }
  __syncthreads();
  if (tid < 8) lbase[tid] = atomicAdd(&counts[tid], lcount[tid]);
  __syncthreads();
  if (tid < 128) {
    int e = ent_e[tid];
    int slot = lbase[e] + ent_slot[tid];
    int t = t0 + (tid >> 1);
    tlist[e * TT + slot] = t;
    glist[e * TT + slot] = ent_g[tid];
  }
}

__global__ void k_offsets(const int* __restrict__ counts, int* __restrict__ offs) {
  if (threadIdx.x == 0) {
    int s = 0;
    for (int e = 0; e < EE; ++e) { offs[e] = s; s += counts[e]; }
  }
}

// ---------------- GEMM1: standard 128x128 GEMM vs interleaved WguT ----------------
// R2-proven 2-barrier structure. A = gathered xb rows, B = WguT (stored rows
// pair gate/up at 16-granularity). Epilogue: acc[m][n] n even = gate frag,
// n+1 = up frag of the SAME logical columns -> silu-combine in-register.
// LDS 33 KB -> 4 blocks/CU.
__global__ __launch_bounds__(256, 4) void k_gemm1(
    const unsigned short* __restrict__ xb,
    const unsigned short* __restrict__ WguT,
    const int* __restrict__ tlist, const float* __restrict__ glist,
    const int* __restrict__ counts, const int* __restrict__ offs,
    unsigned short* __restrict__ hbuf) {
  __shared__ unsigned short lsA[128 * 64];
  __shared__ unsigned short lsB[128 * 64];
  __shared__ int s_tok[128];
  __shared__ float s_gate[128];

  const int e = blockIdx.z;
  const int n_e = counts[e];
  const int row0 = blockIdx.y * 128;
  if (row0 >= n_e) return;
  const int n0 = blockIdx.x * 128;   // stored-row base in WguT
  const int tid = threadIdx.x;

  if (tid < 128) {
    int r = row0 + tid;
    int tok = 0; float gt = 0.f;
    if (r < n_e) { tok = tlist[e * TT + r]; gt = glist[e * TT + r]; }
    s_tok[tid] = tok; s_gate[tid] = gt;
  }
  __syncthreads();

  const int scol = (tid & 7) ^ ((tid >> 3) & 7);
  const unsigned short* srcA[4];
  const unsigned short* srcB[4];
#pragma unroll
  for (int i = 0; i < 4; ++i) {
    int row = i * 32 + (tid >> 3);
    srcA[i] = xb + (size_t)s_tok[row] * HH + scol * 8;
    srcB[i] = WguT + ((size_t)e * 2 * II + n0 + row) * HH + scol * 8;
  }

  f32x4 zero = {0.f, 0.f, 0.f, 0.f};
  f32x4 acc[4][4];
#pragma unroll
  for (int m = 0; m < 4; ++m)
#pragma unroll
    for (int n = 0; n < 4; ++n) acc[m][n] = zero;

  const int l = tid & 63;
  const int w = tid >> 6;
  const int wr = (w >> 1) * 64;
  const int wc = (w & 1) * 64;
  const int lrow = l & 15;
  const int lk = l >> 4;
  const int swz = (l & 7) << 4;
  const int aoff0 = (wr + lrow) * 128 + lk * 16;
  const int boff0 = (wc + lrow) * 128 + lk * 16;
  const char* lcA = (const char*)lsA;
  const char* lcB = (const char*)lsB;

  for (int kt = 0; kt < HH / 64; ++kt) {
#pragma unroll
    for (int i = 0; i < 4; ++i) {
      gload_lds16(srcA[i] + kt * 64, (char*)lsA + i * 4096 + tid * 16);
      gload_lds16(srcB[i] + kt * 64, (char*)lsB + i * 4096 + tid * 16);
    }
    __syncthreads();
#pragma unroll
    for (int kk = 0; kk < 2; ++kk) {
      bf16x8 af[4], bf[4];
#pragma unroll
      for (int m = 0; m < 4; ++m)
        af[m] = *(const bf16x8*)(lcA + ((aoff0 + m * 2048 + kk * 64) ^ swz));
#pragma unroll
      for (int n = 0; n < 4; ++n)
        bf[n] = *(const bf16x8*)(lcB + ((boff0 + n * 2048 + kk * 64) ^ swz));
#pragma unroll
      for (int m = 0; m < 4; ++m)
#pragma unroll
        for (int n = 0; n < 4; ++n)
          acc[m][n] = __builtin_amdgcn_mfma_f32_16x16x32_bf16(af[m], bf[n], acc[m][n], 0, 0, 0);
    }
    __syncthreads();
  }

  const int obase = offs[e];
#pragma unroll
  for (int m = 0; m < 4; ++m)
#pragma unroll
    for (int n = 0; n < 4; n += 2)   // n = gate frag, n+1 = up frag (same cols)
#pragma unroll
      for (int r = 0; r < 4; ++r) {
        int rl = wr + m * 16 + lk * 4 + r;   // C/D: col=lane&15, row=(lane>>4)*4+reg
        if (row0 + rl < n_e) {
          float gv = acc[m][n][r];
          float uv = acc[m][n + 1][r];
          float val = gv / (1.f + __expf(-gv)) * uv * s_gate[rl];
          int L = (n0 >> 1) + (wc >> 1) + (n >> 1) * 16 + lrow;   // logical II col
          hbuf[(size_t)(obase + row0 + rl) * II + L] = f2bf(val);
        }
      }
}

// ---------------- GEMM2: out += h @ Wd (R2-proven, atomic scatter) ----------------
__global__ __launch_bounds__(256, 4) void k_gemm2(
    const unsigned short* __restrict__ hbuf,
    const unsigned short* __restrict__ WdT,   // [E][H][I] (k=I contiguous)
    const int* __restrict__ tlist,
    const int* __restrict__ counts, const int* __restrict__ offs,
    float* __restrict__ out) {
  __shared__ unsigned short lsA[128 * 64];
  __shared__ unsigned short lsB[128 * 64];
  __shared__ int s_tok[128];

  const int e = blockIdx.z;
  const int n_e = counts[e];
  const int row0 = blockIdx.y * 128;
  if (row0 >= n_e) return;
  const int n0 = blockIdx.x * 128;   // H columns
  const int tid = threadIdx.x;
  const int obase = offs[e];

  if (tid < 128) {
    int r = row0 + tid;
    s_tok[tid] = (r < n_e) ? tlist[e * TT + r] : 0;
  }
  __syncthreads();

  const int scol = (tid & 7) ^ ((tid >> 3) & 7);
  const unsigned short* srcA[4];
  const unsigned short* srcB[4];
#pragma unroll
  for (int i = 0; i < 4; ++i) {
    int row = i * 32 + (tid >> 3);
    int ar = obase + row0 + row;
    if (ar > TT * TOPK - 1) ar = TT * TOPK - 1;   // clamp pad rows inside hbuf
    srcA[i] = hbuf + (size_t)ar * II + scol * 8;
    srcB[i] = WdT + ((size_t)e * HH + n0 + row) * II + scol * 8;
  }

  f32x4 zero = {0.f, 0.f, 0.f, 0.f};
  f32x4 acc[4][4];
#pragma unroll
  for (int m = 0; m < 4; ++m)
#pragma unroll
    for (int n = 0; n < 4; ++n) acc[m][n] = zero;

  const int l = tid & 63;
  const int w = tid >> 6;
  const int wr = (w >> 1) * 64;
  const int wc = (w & 1) * 64;
  const int lrow = l & 15;
  const int lk = l >> 4;
  const int swz = (l & 7) << 4;
  const int aoff0 = (wr + lrow) * 128 + lk * 16;
  const int boff0 = (wc + lrow) * 128 + lk * 16;
  const char* lcA = (const char*)lsA;
  const char* lcB = (const char*)lsB;

  for (int kt = 0; kt < II / 64; ++kt) {
#pragma unroll
    for (int i = 0; i < 4; ++i) {
      gload_lds16(srcA[i] + kt * 64, (char*)lsA + i * 4096 + tid * 16);
      gload_lds16(srcB[i] + kt * 64, (char*)lsB + i * 4096 + tid * 16);
    }
    __syncthreads();
#pragma unroll
    for (int kk = 0; kk < 2; ++kk) {
      bf16x8 af[4], bf[4];
#pragma unroll
      for (int m = 0; m < 4; ++m)
        af[m] = *(const bf16x8*)(lcA + ((aoff0 + m * 2048 + kk * 64) ^ swz));
#pragma unroll
      for (int n = 0; n < 4; ++n)
        bf[n] = *(const bf16x8*)(lcB + ((boff0 + n * 2048 + kk * 64) ^ swz));
#pragma unroll
      for (int m = 0; m < 4; ++m)
#pragma unroll
        for (int n = 0; n < 4; ++n)
          acc[m][n] = __builtin_amdgcn_mfma_f32_16x16x32_bf16(af[m], bf[n], acc[m][n], 0, 0, 0);
    }
    __syncthreads();
  }

#pragma unroll
  for (int m = 0; m < 4; ++m)
#pragma unroll
    for (int n = 0; n < 4; ++n)
#pragma unroll
      for (int r = 0; r < 4; ++r) {
        int rl = wr + m * 16 + lk * 4 + r;
        if (row0 + rl < n_e) {
          int t = s_tok[rl];
          unsafeAtomicAdd(&out[(size_t)t * HH + n0 + wc + n * 16 + lrow], acc[m][n][r]);
        }
      }
}

extern "C" void kernel_launch(void* const* d_in, const int* in_sizes, int n_in,
                              void* d_out, int out_size, void* d_ws, size_t ws_size,
                              hipStream_t stream) {
  const float* x  = (const float*)d_in[0];
  const float* Wr = (const float*)d_in[1];
  const float* br = (const float*)d_in[2];
  const float* Wg = (const float*)d_in[3];
  const float* Wu = (const float*)d_in[4];
  const float* Wd = (const float*)d_in[5];
  float* out = (float*)d_out;

  char* ws = (char*)d_ws;
  size_t off = 0;
  auto alloc = [&](size_t bytes) {
    char* p = ws + off;
    off += (bytes + 255) & ~(size_t)255;
    return p;
  };
  unsigned short* xb   = (unsigned short*)alloc((size_t)TT * HH * 2);            // 16 MB
  unsigned short* WguT = (unsigned short*)alloc((size_t)EE * 2 * II * HH * 2);   // 64 MB
  unsigned short* WdT  = (unsigned short*)alloc((size_t)EE * HH * II * 2);       // 32 MB
  unsigned short* hbuf = (unsigned short*)alloc((size_t)TT * TOPK * II * 2);     // 64 MB
  int*   tlist  = (int*)alloc((size_t)EE * TT * 4);
  float* glist  = (float*)alloc((size_t)EE * TT * 4);
  int*   counts = (int*)alloc(128);
  int*   offs   = (int*)alloc(128);

  hipMemsetAsync(counts, 0, 128, stream);
  hipMemsetAsync(d_out, 0, (size_t)TT * HH * 4, stream);

  dim3 tgu(II / 64, HH / 64, EE);   // Wg/Wu -> interleaved WguT
  k_transpose_wgu<<<tgu, 256, 0, stream>>>(Wg, WguT, 0);
  k_transpose_wgu<<<tgu, 256, 0, stream>>>(Wu, WguT, 1);
  dim3 tg2(HH / 64, II / 64, EE);   // Wd: [I][H] -> [H][I]
  k_transpose_cvt<<<tg2, 256, 0, stream>>>(Wd, WdT, II, HH);

  k_router<<<TT / 64, 256, 0, stream>>>(x, Wr, br, xb, tlist, glist, counts);
  k_offsets<<<1, 64, 0, stream>>>(counts, offs);

  dim3 g1(2 * II / 128, TT / 128, EE);   // 32 x 64 x 8, early-exit on empty M-tiles
  k_gemm1<<<g1, 256, 0, stream>>>(xb, WguT, tlist, glist, counts, offs, hbuf);
  dim3 g2(HH / 128, TT / 128, EE);
  k_gemm2<<<g2, 256, 0, stream>>>(hbuf, WdT, tlist, counts, offs, out);

  (void)in_sizes; (void)n_in; (void)out_size; (void)ws_size;
}